// Round 3
// baseline (523.920 us; speedup 1.0000x reference)
//
#include <hip/hip_runtime.h>
#include <math.h>

#define DIMC 512
#define VDIM 256
#define NVARS 320
#define NTOK 32768
#define NELEM (NTOK*DIMC)       // 16777216
#define IDX_OFF NELEM
#define PPL_OFF (NELEM + NTOK*2)
#define KM_OFF (PPL_OFF + 1)

// ws layout: doubles first: dsum[32] (double idx 0..32), dssq[32] (double idx 32..64)
//   == float offsets [0..128). Then float area:
#define OFF_MU   128   // 32 f32
#define OFF_RSTD 160   // 32 f32
#define OFF_LOSS 192   // 1 f32
#define OFF_ESQ  256   // 640 f32 -> [256,896)
#define OFF_HIST 1024  // 640 i32 -> [1024,1664)
#define WS_ZERO_FLOATS 1664

// XOR-swizzled LDS index: conceptual [k][col], physical col4' = col4 ^ (k>>2)
__device__ __forceinline__ int sw128(int k, int col) {
    return k * 128 + ((((col >> 2) ^ (k >> 2)) & 31) << 2) + (col & 3);
}

__global__ void k_init(float* ws) {
    int i = blockIdx.x * 256 + threadIdx.x;
    if (i < WS_ZERO_FLOATS) ws[i] = 0.0f;
}

// e_sq[v*2+g] = sum_d emb[v][g][d]^2, fp64 accumulate -> correctly-rounded f32
__global__ void k_esq(const float* __restrict__ emb, float* ws) {
    int wave = blockIdx.x * 4 + (threadIdx.x >> 6);
    int lane = threadIdx.x & 63;
    const float* p = emb + (size_t)wave * VDIM;
    double s = 0.0;
    for (int j = lane; j < VDIM; j += 64) { double v = (double)p[j]; s += v * v; }
    for (int off = 32; off; off >>= 1) s += __shfl_down(s, off);
    if (lane == 0) ws[OFF_ESQ + wave] = (float)s;
}

// y_t = (x @ W^T)^T per group: writes y_t[g*256+o][tok] (transposed!) into `yt`.
// Tile 128 tok x 128 o, K=256 in 64-chunks, fused GN stats (fp64 atomics).
__global__ __launch_bounds__(256, 2) void k_gemm(const float* __restrict__ x,
                                                 const float* __restrict__ w,
                                                 float* __restrict__ yt, float* ws) {
    __shared__ float As[64 * 128];   // swizzled [k][tok]
    __shared__ float Ws[64 * 128];   // swizzled [k][o]
    __shared__ double red1[256];
    __shared__ double red2[256];
    const int tid = threadIdx.x;
    const int tx = tid & 15, ty = tid >> 4;
    const int tok0 = blockIdx.x * 128;
    const int o0 = blockIdx.y * 128;
    const int g = blockIdx.z;
    const int b = tok0 >> 11;

    float acc[8][8];
#pragma unroll
    for (int i = 0; i < 8; i++)
#pragma unroll
        for (int j = 0; j < 8; j++) acc[i][j] = 0.0f;

    for (int kc = 0; kc < 4; kc++) {
        __syncthreads();
#pragma unroll
        for (int it = 0; it < 8; it++) {
            const int tok = ty + 16 * it;
            float4 v = *(const float4*)(x + (size_t)(tok0 + tok) * DIMC + g * VDIM + kc * 64 + tx * 4);
            As[sw128(tx * 4 + 0, tok)] = v.x; As[sw128(tx * 4 + 1, tok)] = v.y;
            As[sw128(tx * 4 + 2, tok)] = v.z; As[sw128(tx * 4 + 3, tok)] = v.w;
        }
#pragma unroll
        for (int it = 0; it < 8; it++) {
            const int o = ty + 16 * it;
            float4 v = *(const float4*)(w + (size_t)(g * 256 + o0 + o) * 256 + kc * 64 + tx * 4);
            Ws[sw128(tx * 4 + 0, o)] = v.x; Ws[sw128(tx * 4 + 1, o)] = v.y;
            Ws[sw128(tx * 4 + 2, o)] = v.z; Ws[sw128(tx * 4 + 3, o)] = v.w;
        }
        __syncthreads();
        const float4* A4 = (const float4*)As;
        const float4* W4 = (const float4*)Ws;
#pragma unroll 4
        for (int k = 0; k < 64; k++) {
            const int kk = k >> 2;
            float4 a0 = A4[k * 32 + ((2 * ty) ^ kk)];
            float4 a1 = A4[k * 32 + ((2 * ty + 1) ^ kk)];
            float4 b0 = W4[k * 32 + (tx ^ kk)];
            float4 b1 = W4[k * 32 + ((16 + tx) ^ kk)];
            float av[8] = {a0.x, a0.y, a0.z, a0.w, a1.x, a1.y, a1.z, a1.w};
            float bv[8] = {b0.x, b0.y, b0.z, b0.w, b1.x, b1.y, b1.z, b1.w};
#pragma unroll
            for (int i = 0; i < 8; i++)
#pragma unroll
                for (int j = 0; j < 8; j++) acc[i][j] = fmaf(av[i], bv[j], acc[i][j]);
        }
    }
    // epilogue: fp64 stats + transposed y_t stores (8 toks contiguous per o)
    double s1 = 0.0, s2 = 0.0;
#pragma unroll
    for (int i = 0; i < 8; i++)
#pragma unroll
        for (int j = 0; j < 8; j++) {
            s1 += (double)acc[i][j];
            s2 += (double)acc[i][j] * acc[i][j];
        }
#pragma unroll
    for (int j = 0; j < 8; j++) {
        const int o = o0 + ((j < 4) ? (tx * 4 + j) : (64 + tx * 4 + (j - 4)));
        float4 lo = make_float4(acc[0][j], acc[1][j], acc[2][j], acc[3][j]);
        float4 hi = make_float4(acc[4][j], acc[5][j], acc[6][j], acc[7][j]);
        float* p = yt + (size_t)(g * 256 + o) * NTOK + tok0 + ty * 8;
        *(float4*)p = lo;
        *(float4*)(p + 4) = hi;
    }
    red1[tid] = s1; red2[tid] = s2;
    __syncthreads();
    for (int s = 128; s; s >>= 1) {
        if (tid < s) { red1[tid] += red1[tid + s]; red2[tid] += red2[tid + s]; }
        __syncthreads();
    }
    if (tid == 0) {
        double* dws = (double*)ws;
        atomicAdd(&dws[b * 2 + g], red1[0]);
        atomicAdd(&dws[32 + b * 2 + g], red2[0]);
    }
}

__global__ void k_stats(float* ws) {
    int i = threadIdx.x;
    if (i < 32) {
        const double* d = (const double*)ws;
        double mu = d[i] * (1.0 / 524288.0);
        double var = d[32 + i] * (1.0 / 524288.0) - mu * mu;
        float varf = (float)var;
        ws[OFF_MU + i] = (float)mu;
        ws[OFF_RSTD + i] = 1.0f / sqrtf(varf + 1e-5f);
    }
}

// Single-pass VQ, 256 threads / 128 tok per block. All 320 codes resident in
// LDS per k-chunk; acc[5][8][4] = 160 f32 per thread. Round-1/2 lesson: an
// 8-wave (512-thr) workgroup gets capped at 128 arch VGPRs -> accumulator
// spills -> 241-262 us. A 4-wave workgroup runs 1 wave/SIMD, so each wave may
// use the full 256-VGPR budget: ~200 live regs, zero spill. LDS = 32K As +
// 80K Es = 112.5 KB -> 1 block/CU. Latency hiding comes from ILP (7 ds_reads
// per 320 FMA cycles, reads heavily lane-broadcast).
// Numerics bit-identical to the 423-us round-0 version: per-(tok,v) FMA chain
// visits k in kc-major/k-minor ascending order; d2 = fl(fl(zsq-2*dot)+esq),
// ties -> lowest v; zsq fp64 chain order unchanged.
__global__ __launch_bounds__(256, 1) void k_vq(const float* __restrict__ emb,
                                               const float* __restrict__ gnw,
                                               const float* __restrict__ gnb,
                                               float* out, float* ws) {
    __shared__ float As[64 * 128];   // swizzled [k][tok]   32 KB
    __shared__ float Es[64 * 320];   // swizzled [k][v]     80 KB
    __shared__ float zsqs[128];
    __shared__ float lsum[16];

    const int tid = threadIdx.x;
    const int tx = tid & 15, ty = tid >> 4;    // 16 x 16
    const int ks = tid >> 2;                   // staging row 0..63
    const int tq = tid & 3;
    const int tok0 = blockIdx.x * 128;
    const int g = blockIdx.y;
    const int b = tok0 >> 11;
    const float mu = ws[OFF_MU + b * 2 + g];
    const float rstd = ws[OFF_RSTD + b * 2 + g];
    int* hist = ((int*)ws) + OFF_HIST;
    const float* yt = out;           // y_t[g*256+k][NTOK]

    float acc[5][8][4];
#pragma unroll
    for (int p = 0; p < 5; p++)
#pragma unroll
        for (int i = 0; i < 8; i++)
#pragma unroll
            for (int j = 0; j < 4; j++) acc[p][i][j] = 0.0f;
    double zacc = 0.0;

    for (int kc = 0; kc < 4; kc++) {
        __syncthreads();
        // ---- stage As: thread owns k-row ks (4 thr/row); 8 float4 along tok ----
        {
            const float sgw = gnw[g * VDIM + kc * 64 + ks];
            const float sgb = gnb[g * VDIM + kc * 64 + ks];
            const float* yrow = yt + (size_t)(g * 256 + kc * 64 + ks) * NTOK + tok0;
            const int k4s = ks >> 2;
#pragma unroll
            for (int it = 0; it < 8; it++) {
                const int t4 = it * 4 + tq;      // tok-quad 0..31
                float4 v = *(const float4*)(yrow + t4 * 4);
                float z0 = fmaf((v.x - mu) * rstd, sgw, sgb);
                float z1 = fmaf((v.y - mu) * rstd, sgw, sgb);
                float z2 = fmaf((v.z - mu) * rstd, sgw, sgb);
                float z3 = fmaf((v.w - mu) * rstd, sgw, sgb);
                ((float4*)As)[ks * 32 + ((t4 ^ k4s) & 31)] = make_float4(z0, z1, z2, z3);
            }
        }
        // ---- stage Es: thread owns v-row ks (4 thr/row); transpose to Es[k][v] ----
        {
            const int vr = ks;                   // 0..63
#pragma unroll
            for (int p = 0; p < 5; p++) {
                const float* erow = emb + (size_t)((p * 64 + vr) * 2 + g) * VDIM + kc * 64;
#pragma unroll
                for (int f = 0; f < 4; f++) {
                    const int f4 = f * 4 + tq;   // k-quad 0..15 (contiguous per instr)
                    float4 e = *(const float4*)(erow + f4 * 4);
                    const int k0 = f4 * 4;
                    const int c4 = p * 16 + (((vr >> 2) ^ f4) & 15);
                    const int base = c4 * 4 + (vr & 3);
                    Es[(k0 + 0) * 320 + base] = e.x;
                    Es[(k0 + 1) * 320 + base] = e.y;
                    Es[(k0 + 2) * 320 + base] = e.z;
                    Es[(k0 + 3) * 320 + base] = e.w;
                }
            }
        }
        __syncthreads();
        // ---- zsq pass: tok=tid<128, serial k order, fp64 (same chain as before) ----
        if (tid < 128) {
            const int c4z = tid >> 2, cl = tid & 3;
            for (int k = 0; k < 64; k++) {
                float z = As[k * 128 + (((c4z ^ (k >> 2)) & 31) << 2) + cl];
                zacc += (double)z * z;
            }
        }
        // ---- compute: per k, 2 A-reads + 5 E-reads feed 160 FMAs ----
        const float4* A4 = (const float4*)As;
        const float4* E4 = (const float4*)Es;
#pragma unroll 2
        for (int k = 0; k < 64; k++) {
            const int kk = k >> 2;
            float4 a0 = A4[k * 32 + ((2 * ty) ^ kk)];
            float4 a1 = A4[k * 32 + ((2 * ty + 1) ^ kk)];
            float av[8] = {a0.x, a0.y, a0.z, a0.w, a1.x, a1.y, a1.z, a1.w};
#pragma unroll
            for (int p = 0; p < 5; p++) {
                float4 e4 = E4[k * 80 + p * 16 + (tx ^ kk)];
                float ev[4] = {e4.x, e4.y, e4.z, e4.w};
#pragma unroll
                for (int i = 0; i < 8; i++)
#pragma unroll
                    for (int j = 0; j < 4; j++)
                        acc[p][i][j] = fmaf(av[i], ev[j], acc[p][i][j]);
            }
        }
    }
    if (tid < 128) zsqs[tid] = (float)zacc;
    __syncthreads();
    float zs[8];
#pragma unroll
    for (int i = 0; i < 8; i++) zs[i] = zsqs[ty * 8 + i];

    // fold argmin: d2 = fl(fl(zsq - 2*dot) + esq); ties -> lowest v (vt asc, j asc)
    float br[8]; int bv[8];
#pragma unroll
    for (int i = 0; i < 8; i++) { br[i] = 3.0e38f; bv[i] = 0; }
#pragma unroll
    for (int vt = 0; vt < 5; vt++) {
        float esql[4];
#pragma unroll
        for (int j = 0; j < 4; j++) esql[j] = ws[OFF_ESQ + (size_t)(vt * 64 + tx * 4 + j) * 2 + g];
#pragma unroll
        for (int i = 0; i < 8; i++)
#pragma unroll
            for (int j = 0; j < 4; j++) {
                float t = zs[i] - 2.0f * acc[vt][i][j];
                float d2 = t + esql[j];
                int v = vt * 64 + tx * 4 + j;
                if (d2 < br[i]) { br[i] = d2; bv[i] = v; }
            }
    }
    // cross-thread (tx) lexicographic min, 16-wide shfl
#pragma unroll
    for (int i = 0; i < 8; i++) {
#pragma unroll
        for (int off = 8; off; off >>= 1) {
            float r2 = __shfl_down(br[i], off, 16);
            int v2 = __shfl_down(bv[i], off, 16);
            if (r2 < br[i] || (r2 == br[i] && v2 < bv[i])) { br[i] = r2; bv[i] = v2; }
        }
    }
    float dlocal = 0.0f;
    if (tx == 0) {
#pragma unroll
        for (int i = 0; i < 8; i++) {
            const int tok = ty * 8 + i;
            out[IDX_OFF + (size_t)(tok0 + tok) * 2 + g] = (float)bv[i];
            atomicAdd(&hist[g * 320 + bv[i]], 1);
            dlocal += br[i];
        }
        lsum[ty] = dlocal;
    }
    __syncthreads();
    if (tid == 0) {
        float s = 0.0f;
        for (int t = 0; t < 16; t++) s += lsum[t];
        atomicAdd(&ws[OFF_LOSS], s);
    }
}

// x_out = zq gather: reads idx from out's idx region, overwrites y_t region with zq.
// Separate kernel => global barrier vs k_vq's y_t reads (y_t aliases x_out region).
__global__ __launch_bounds__(256) void k_gather(const float* __restrict__ emb,
                                                float* out) {
    __shared__ int sidx[128];
    const int tid = threadIdx.x;
    const int tok0 = blockIdx.x * 64;
    if (tid < 128) sidx[tid] = (int)out[IDX_OFF + (size_t)tok0 * 2 + tid];
    __syncthreads();
#pragma unroll 4
    for (int it = 0; it < 32; it++) {
        const int j = it * 256 + tid;
        const int tl = j >> 7;           // token within block (0..63)
        const int c4 = j & 127;          // float4 index within row (0..127)
        const int g = c4 >> 6;
        const int v = sidx[tl * 2 + g];
        float4 e = *(const float4*)(emb + (size_t)(v * 2 + g) * VDIM + (c4 & 63) * 4);
        *(float4*)(out + (size_t)(tok0 + tl) * DIMC + c4 * 4) = e;
    }
}

__global__ void k_final(float* out, float* ws) {
    __shared__ float red[512];
    int tid = threadIdx.x;
    int* hist = ((int*)ws) + OFF_HIST;
    float ppl = 0.0f;
    for (int g = 0; g < 2; g++) {
        float term = 0.0f;
        if (tid < 320) {
            float p = (float)hist[g * 320 + tid] * (1.0f / 32768.0f);
            term = p * logf(p + 1e-7f);
        }
        red[tid] = term;
        __syncthreads();
        for (int s = 256; s; s >>= 1) {
            if (tid < s) red[tid] += red[tid + s];
            __syncthreads();
        }
        if (tid == 0) ppl += expf(-red[0]);
        __syncthreads();
    }
    if (tid == 0) {
        out[PPL_OFF] = ppl;
        out[KM_OFF] = 1.25f * ws[OFF_LOSS] / 16777216.0f;
    }
}

extern "C" void kernel_launch(void* const* d_in, const int* in_sizes, int n_in,
                              void* d_out, int out_size, void* d_ws, size_t ws_size,
                              hipStream_t stream) {
    (void)in_sizes; (void)n_in; (void)out_size; (void)ws_size;
    const float* x      = (const float*)d_in[0];
    const float* conv_w = (const float*)d_in[1];
    const float* gn_w   = (const float*)d_in[2];
    const float* gn_b   = (const float*)d_in[3];
    const float* emb    = (const float*)d_in[4];
    float* out = (float*)d_out;
    float* ws  = (float*)d_ws;

    hipLaunchKernelGGL(k_init,   dim3(7),         dim3(256), 0, stream, ws);
    hipLaunchKernelGGL(k_esq,    dim3(160),       dim3(256), 0, stream, emb, ws);
    hipLaunchKernelGGL(k_gemm,   dim3(256, 2, 2), dim3(256), 0, stream, x, conv_w, out, ws);
    hipLaunchKernelGGL(k_stats,  dim3(1),         dim3(64),  0, stream, ws);
    hipLaunchKernelGGL(k_vq,     dim3(256, 2),    dim3(256), 0, stream, emb, gn_w, gn_b, out, ws);
    hipLaunchKernelGGL(k_gather, dim3(512),       dim3(256), 0, stream, emb, out);
    hipLaunchKernelGGL(k_final,  dim3(1),         dim3(512), 0, stream, out, ws);
}

// Round 4
// 416.803 us; speedup vs baseline: 1.2570x; 1.2570x over previous
//
#include <hip/hip_runtime.h>
#include <math.h>

#define DIMC 512
#define VDIM 256
#define NVARS 320
#define NTOK 32768
#define NELEM (NTOK*DIMC)       // 16777216
#define IDX_OFF NELEM
#define PPL_OFF (NELEM + NTOK*2)
#define KM_OFF (PPL_OFF + 1)

// ws layout: doubles first: dsum[32] (double idx 0..32), dssq[32] (double idx 32..64)
//   == float offsets [0..128). Then float area:
#define OFF_MU   128   // 32 f32
#define OFF_RSTD 160   // 32 f32
#define OFF_LOSS 192   // 1 f32
#define OFF_ESQ  256   // 640 f32 -> [256,896)
#define OFF_HIST 1024  // 640 i32 -> [1024,1664)
#define WS_ZERO_FLOATS 1664

// XOR-swizzled LDS index: conceptual [k][col], physical col4' = col4 ^ (k>>2)
__device__ __forceinline__ int sw128(int k, int col) {
    return k * 128 + ((((col >> 2) ^ (k >> 2)) & 31) << 2) + (col & 3);
}

__global__ void k_init(float* ws) {
    int i = blockIdx.x * 256 + threadIdx.x;
    if (i < WS_ZERO_FLOATS) ws[i] = 0.0f;
}

// e_sq[v*2+g] = sum_d emb[v][g][d]^2, fp64 accumulate -> correctly-rounded f32
__global__ void k_esq(const float* __restrict__ emb, float* ws) {
    int wave = blockIdx.x * 4 + (threadIdx.x >> 6);
    int lane = threadIdx.x & 63;
    const float* p = emb + (size_t)wave * VDIM;
    double s = 0.0;
    for (int j = lane; j < VDIM; j += 64) { double v = (double)p[j]; s += v * v; }
    for (int off = 32; off; off >>= 1) s += __shfl_down(s, off);
    if (lane == 0) ws[OFF_ESQ + wave] = (float)s;
}

// y_t = (x @ W^T)^T per group: writes y_t[g*256+o][tok] (transposed!) into `yt`.
// Tile 128 tok x 128 o, K=256 in 64-chunks, fused GN stats (fp64 atomics).
__global__ __launch_bounds__(256, 2) void k_gemm(const float* __restrict__ x,
                                                 const float* __restrict__ w,
                                                 float* __restrict__ yt, float* ws) {
    __shared__ float As[64 * 128];   // swizzled [k][tok]
    __shared__ float Ws[64 * 128];   // swizzled [k][o]
    __shared__ double red1[256];
    __shared__ double red2[256];
    const int tid = threadIdx.x;
    const int tx = tid & 15, ty = tid >> 4;
    const int tok0 = blockIdx.x * 128;
    const int o0 = blockIdx.y * 128;
    const int g = blockIdx.z;
    const int b = tok0 >> 11;

    float acc[8][8];
#pragma unroll
    for (int i = 0; i < 8; i++)
#pragma unroll
        for (int j = 0; j < 8; j++) acc[i][j] = 0.0f;

    for (int kc = 0; kc < 4; kc++) {
        __syncthreads();
#pragma unroll
        for (int it = 0; it < 8; it++) {
            const int tok = ty + 16 * it;
            float4 v = *(const float4*)(x + (size_t)(tok0 + tok) * DIMC + g * VDIM + kc * 64 + tx * 4);
            As[sw128(tx * 4 + 0, tok)] = v.x; As[sw128(tx * 4 + 1, tok)] = v.y;
            As[sw128(tx * 4 + 2, tok)] = v.z; As[sw128(tx * 4 + 3, tok)] = v.w;
        }
#pragma unroll
        for (int it = 0; it < 8; it++) {
            const int o = ty + 16 * it;
            float4 v = *(const float4*)(w + (size_t)(g * 256 + o0 + o) * 256 + kc * 64 + tx * 4);
            Ws[sw128(tx * 4 + 0, o)] = v.x; Ws[sw128(tx * 4 + 1, o)] = v.y;
            Ws[sw128(tx * 4 + 2, o)] = v.z; Ws[sw128(tx * 4 + 3, o)] = v.w;
        }
        __syncthreads();
        const float4* A4 = (const float4*)As;
        const float4* W4 = (const float4*)Ws;
#pragma unroll 4
        for (int k = 0; k < 64; k++) {
            const int kk = k >> 2;
            float4 a0 = A4[k * 32 + ((2 * ty) ^ kk)];
            float4 a1 = A4[k * 32 + ((2 * ty + 1) ^ kk)];
            float4 b0 = W4[k * 32 + (tx ^ kk)];
            float4 b1 = W4[k * 32 + ((16 + tx) ^ kk)];
            float av[8] = {a0.x, a0.y, a0.z, a0.w, a1.x, a1.y, a1.z, a1.w};
            float bv[8] = {b0.x, b0.y, b0.z, b0.w, b1.x, b1.y, b1.z, b1.w};
#pragma unroll
            for (int i = 0; i < 8; i++)
#pragma unroll
                for (int j = 0; j < 8; j++) acc[i][j] = fmaf(av[i], bv[j], acc[i][j]);
        }
    }
    // epilogue: fp64 stats + transposed y_t stores (8 toks contiguous per o)
    double s1 = 0.0, s2 = 0.0;
#pragma unroll
    for (int i = 0; i < 8; i++)
#pragma unroll
        for (int j = 0; j < 8; j++) {
            s1 += (double)acc[i][j];
            s2 += (double)acc[i][j] * acc[i][j];
        }
#pragma unroll
    for (int j = 0; j < 8; j++) {
        const int o = o0 + ((j < 4) ? (tx * 4 + j) : (64 + tx * 4 + (j - 4)));
        float4 lo = make_float4(acc[0][j], acc[1][j], acc[2][j], acc[3][j]);
        float4 hi = make_float4(acc[4][j], acc[5][j], acc[6][j], acc[7][j]);
        float* p = yt + (size_t)(g * 256 + o) * NTOK + tok0 + ty * 8;
        *(float4*)p = lo;
        *(float4*)(p + 4) = hi;
    }
    red1[tid] = s1; red2[tid] = s2;
    __syncthreads();
    for (int s = 128; s; s >>= 1) {
        if (tid < s) { red1[tid] += red1[tid + s]; red2[tid] += red2[tid + s]; }
        __syncthreads();
    }
    if (tid == 0) {
        double* dws = (double*)ws;
        atomicAdd(&dws[b * 2 + g], red1[0]);
        atomicAdd(&dws[32 + b * 2 + g], red2[0]);
    }
}

__global__ void k_stats(float* ws) {
    int i = threadIdx.x;
    if (i < 32) {
        const double* d = (const double*)ws;
        double mu = d[i] * (1.0 / 524288.0);
        double var = d[32 + i] * (1.0 / 524288.0) - mu * mu;
        float varf = (float)var;
        ws[OFF_MU + i] = (float)mu;
        ws[OFF_RSTD + i] = 1.0f / sqrtf(varf + 1e-5f);
    }
}

// VQ, k_gemm-shaped: 2.5 passes over v (128+128+64), tile 128 tok x 128 v,
// acc[8][8] = 64 regs (k_gemm-proven pressure, no spill at (256,2)).
// Per k-step: 4 ds_read_b128 per 64 FMAs (128 issue-cyc) vs round-0's 3 per
// 32 FMAs -> LDS-issue demand halves; ceiling moves from ~46% to ~70-100%
// VALU. LDS = 32K As + 32K Es = 64.6 KB -> 2 blocks/CU = 2 waves/SIMD (TLP).
// Round-1/3 lesson: allocator won't exceed ~136 VGPR regardless of bounds,
// so the accumulator must fit in ~64 regs. Numerics bit-identical to all
// passing rounds: per-(tok,v) FMA chain visits k in kc-major/k-minor
// ascending order; d2 = fl(fl(zsq-2*dot)+esq); fold order globally
// ascending v; zsq fp64 chain unchanged; lex-min shfl reduction unchanged.
__global__ __launch_bounds__(256, 2) void k_vq(const float* __restrict__ emb,
                                               const float* __restrict__ gnw,
                                               const float* __restrict__ gnb,
                                               float* out, float* ws) {
    __shared__ float As[64 * 128];   // swizzled [k][tok]  32 KB
    __shared__ float Es[64 * 128];   // swizzled [k][v]    32 KB
    __shared__ float zsqs[128];
    __shared__ float lsum[16];

    const int tid = threadIdx.x;
    const int tx = tid & 15, ty = tid >> 4;    // 16 x 16
    const int ks = tid >> 2;                   // As staging row 0..63
    const int tq = tid & 3;
    const int tok0 = blockIdx.x * 128;
    const int g = blockIdx.y;
    const int b = tok0 >> 11;
    const float mu = ws[OFF_MU + b * 2 + g];
    const float rstd = ws[OFF_RSTD + b * 2 + g];
    int* hist = ((int*)ws) + OFF_HIST;
    const float* yt = out;           // y_t[g*256+k][NTOK]

    float br[8]; int bv[8]; float zs[8];
#pragma unroll
    for (int i = 0; i < 8; i++) { br[i] = 3.0e38f; bv[i] = 0; }
    double zacc = 0.0;

    // ---- passes 0,1: v-tiles [0,128) and [128,256), acc[8][8] ----
    for (int pass = 0; pass < 2; pass++) {
        const int vbase = pass * 128;
        float acc[8][8];
#pragma unroll
        for (int i = 0; i < 8; i++)
#pragma unroll
            for (int j = 0; j < 8; j++) acc[i][j] = 0.0f;

        for (int kc = 0; kc < 4; kc++) {
            __syncthreads();
            // stage As: thread owns k-row ks (4 thr/row); 8 float4 along tok; affine fused
            {
                const float sgw = gnw[g * VDIM + kc * 64 + ks];
                const float sgb = gnb[g * VDIM + kc * 64 + ks];
                const float* yrow = yt + (size_t)(g * 256 + kc * 64 + ks) * NTOK + tok0;
                const int k4s = ks >> 2;
#pragma unroll
                for (int it = 0; it < 8; it++) {
                    const int t4 = it * 4 + tq;      // tok-quad 0..31
                    float4 v = *(const float4*)(yrow + t4 * 4);
                    float z0 = fmaf((v.x - mu) * rstd, sgw, sgb);
                    float z1 = fmaf((v.y - mu) * rstd, sgw, sgb);
                    float z2 = fmaf((v.z - mu) * rstd, sgw, sgb);
                    float z3 = fmaf((v.w - mu) * rstd, sgw, sgb);
                    ((float4*)As)[ks * 32 + ((t4 ^ k4s) & 31)] = make_float4(z0, z1, z2, z3);
                }
            }
            // stage Es: k_gemm Ws-style; 128 v-rows, row-major emb -> swizzled [k][v]
#pragma unroll
            for (int it = 0; it < 8; it++) {
                const int vr = ty + 16 * it;
                float4 e = *(const float4*)(emb + (size_t)((vbase + vr) * 2 + g) * VDIM + kc * 64 + tx * 4);
                Es[sw128(tx * 4 + 0, vr)] = e.x; Es[sw128(tx * 4 + 1, vr)] = e.y;
                Es[sw128(tx * 4 + 2, vr)] = e.z; Es[sw128(tx * 4 + 3, vr)] = e.w;
            }
            __syncthreads();
            // zsq (pass 0 only): tok=tid<128, serial k order, fp64
            if (pass == 0 && tid < 128) {
                const int c4z = tid >> 2, cl = tid & 3;
                for (int k = 0; k < 64; k++) {
                    float z = As[k * 128 + (((c4z ^ (k >> 2)) & 31) << 2) + cl];
                    zacc += (double)z * z;
                }
            }
            // compute: 4 b128 reads per 64 FMAs
            const float4* A4 = (const float4*)As;
            const float4* E4 = (const float4*)Es;
#pragma unroll 4
            for (int k = 0; k < 64; k++) {
                const int kk = k >> 2;
                float4 a0 = A4[k * 32 + ((2 * ty) ^ kk)];
                float4 a1 = A4[k * 32 + ((2 * ty + 1) ^ kk)];
                float4 e0 = E4[k * 32 + (tx ^ kk)];
                float4 e1 = E4[k * 32 + ((16 + tx) ^ kk)];
                float av[8] = {a0.x, a0.y, a0.z, a0.w, a1.x, a1.y, a1.z, a1.w};
                float ev[8] = {e0.x, e0.y, e0.z, e0.w, e1.x, e1.y, e1.z, e1.w};
#pragma unroll
                for (int i = 0; i < 8; i++)
#pragma unroll
                    for (int j = 0; j < 8; j++)
                        acc[i][j] = fmaf(av[i], ev[j], acc[i][j]);
            }
        }
        if (pass == 0) {
            if (tid < 128) zsqs[tid] = (float)zacc;
            __syncthreads();
#pragma unroll
            for (int i = 0; i < 8; i++) zs[i] = zsqs[ty * 8 + i];
        }
        // fold: ascending v within thread (j<4: vbase+tx*4+j; j>=4: vbase+64+tx*4+j-4)
        float esql[8];
#pragma unroll
        for (int j = 0; j < 4; j++) esql[j] = ws[OFF_ESQ + (size_t)(vbase + tx * 4 + j) * 2 + g];
#pragma unroll
        for (int j = 4; j < 8; j++) esql[j] = ws[OFF_ESQ + (size_t)(vbase + 64 + tx * 4 + (j - 4)) * 2 + g];
#pragma unroll
        for (int i = 0; i < 8; i++)
#pragma unroll
            for (int j = 0; j < 8; j++) {
                float t = zs[i] - 2.0f * acc[i][j];
                float d2 = t + esql[j];
                int v = (j < 4) ? (vbase + tx * 4 + j) : (vbase + 64 + tx * 4 + (j - 4));
                if (d2 < br[i]) { br[i] = d2; bv[i] = v; }
            }
    }

    // ---- pass 2: v-tile [256,320), 64 wide, acc[8][4] ----
    {
        float acc[8][4];
#pragma unroll
        for (int i = 0; i < 8; i++)
#pragma unroll
            for (int j = 0; j < 4; j++) acc[i][j] = 0.0f;

        for (int kc = 0; kc < 4; kc++) {
            __syncthreads();
            {
                const float sgw = gnw[g * VDIM + kc * 64 + ks];
                const float sgb = gnb[g * VDIM + kc * 64 + ks];
                const float* yrow = yt + (size_t)(g * 256 + kc * 64 + ks) * NTOK + tok0;
                const int k4s = ks >> 2;
#pragma unroll
                for (int it = 0; it < 8; it++) {
                    const int t4 = it * 4 + tq;
                    float4 v = *(const float4*)(yrow + t4 * 4);
                    float z0 = fmaf((v.x - mu) * rstd, sgw, sgb);
                    float z1 = fmaf((v.y - mu) * rstd, sgw, sgb);
                    float z2 = fmaf((v.z - mu) * rstd, sgw, sgb);
                    float z3 = fmaf((v.w - mu) * rstd, sgw, sgb);
                    ((float4*)As)[ks * 32 + ((t4 ^ k4s) & 31)] = make_float4(z0, z1, z2, z3);
                }
            }
            // stage Es: 64 v-rows only (cols 0..63 of Es; swizzle keeps col4^kk in 0..15)
#pragma unroll
            for (int it = 0; it < 4; it++) {
                const int vr = ty + 16 * it;     // 0..63
                float4 e = *(const float4*)(emb + (size_t)((256 + vr) * 2 + g) * VDIM + kc * 64 + tx * 4);
                Es[sw128(tx * 4 + 0, vr)] = e.x; Es[sw128(tx * 4 + 1, vr)] = e.y;
                Es[sw128(tx * 4 + 2, vr)] = e.z; Es[sw128(tx * 4 + 3, vr)] = e.w;
            }
            __syncthreads();
            const float4* A4 = (const float4*)As;
            const float4* E4 = (const float4*)Es;
#pragma unroll 4
            for (int k = 0; k < 64; k++) {
                const int kk = k >> 2;
                float4 a0 = A4[k * 32 + ((2 * ty) ^ kk)];
                float4 a1 = A4[k * 32 + ((2 * ty + 1) ^ kk)];
                float4 e0 = E4[k * 32 + (tx ^ kk)];
                float av[8] = {a0.x, a0.y, a0.z, a0.w, a1.x, a1.y, a1.z, a1.w};
                float ev[4] = {e0.x, e0.y, e0.z, e0.w};
#pragma unroll
                for (int i = 0; i < 8; i++)
#pragma unroll
                    for (int j = 0; j < 4; j++)
                        acc[i][j] = fmaf(av[i], ev[j], acc[i][j]);
            }
        }
        float esql[4];
#pragma unroll
        for (int j = 0; j < 4; j++) esql[j] = ws[OFF_ESQ + (size_t)(256 + tx * 4 + j) * 2 + g];
#pragma unroll
        for (int i = 0; i < 8; i++)
#pragma unroll
            for (int j = 0; j < 4; j++) {
                float t = zs[i] - 2.0f * acc[i][j];
                float d2 = t + esql[j];
                int v = 256 + tx * 4 + j;
                if (d2 < br[i]) { br[i] = d2; bv[i] = v; }
            }
    }

    // cross-thread (tx) lexicographic min, 16-wide shfl
#pragma unroll
    for (int i = 0; i < 8; i++) {
#pragma unroll
        for (int off = 8; off; off >>= 1) {
            float r2 = __shfl_down(br[i], off, 16);
            int v2 = __shfl_down(bv[i], off, 16);
            if (r2 < br[i] || (r2 == br[i] && v2 < bv[i])) { br[i] = r2; bv[i] = v2; }
        }
    }
    float dlocal = 0.0f;
    if (tx == 0) {
#pragma unroll
        for (int i = 0; i < 8; i++) {
            const int tok = ty * 8 + i;
            out[IDX_OFF + (size_t)(tok0 + tok) * 2 + g] = (float)bv[i];
            atomicAdd(&hist[g * 320 + bv[i]], 1);
            dlocal += br[i];
        }
        lsum[ty] = dlocal;
    }
    __syncthreads();
    if (tid == 0) {
        float s = 0.0f;
        for (int t = 0; t < 16; t++) s += lsum[t];
        atomicAdd(&ws[OFF_LOSS], s);
    }
}

// x_out = zq gather: reads idx from out's idx region, overwrites y_t region with zq.
// Separate kernel => global barrier vs k_vq's y_t reads (y_t aliases x_out region).
__global__ __launch_bounds__(256) void k_gather(const float* __restrict__ emb,
                                                float* out) {
    __shared__ int sidx[128];
    const int tid = threadIdx.x;
    const int tok0 = blockIdx.x * 64;
    if (tid < 128) sidx[tid] = (int)out[IDX_OFF + (size_t)tok0 * 2 + tid];
    __syncthreads();
#pragma unroll 4
    for (int it = 0; it < 32; it++) {
        const int j = it * 256 + tid;
        const int tl = j >> 7;           // token within block (0..63)
        const int c4 = j & 127;          // float4 index within row (0..127)
        const int g = c4 >> 6;
        const int v = sidx[tl * 2 + g];
        float4 e = *(const float4*)(emb + (size_t)(v * 2 + g) * VDIM + (c4 & 63) * 4);
        *(float4*)(out + (size_t)(tok0 + tl) * DIMC + c4 * 4) = e;
    }
}

__global__ void k_final(float* out, float* ws) {
    __shared__ float red[512];
    int tid = threadIdx.x;
    int* hist = ((int*)ws) + OFF_HIST;
    float ppl = 0.0f;
    for (int g = 0; g < 2; g++) {
        float term = 0.0f;
        if (tid < 320) {
            float p = (float)hist[g * 320 + tid] * (1.0f / 32768.0f);
            term = p * logf(p + 1e-7f);
        }
        red[tid] = term;
        __syncthreads();
        for (int s = 256; s; s >>= 1) {
            if (tid < s) red[tid] += red[tid + s];
            __syncthreads();
        }
        if (tid == 0) ppl += expf(-red[0]);
        __syncthreads();
    }
    if (tid == 0) {
        out[PPL_OFF] = ppl;
        out[KM_OFF] = 1.25f * ws[OFF_LOSS] / 16777216.0f;
    }
}

extern "C" void kernel_launch(void* const* d_in, const int* in_sizes, int n_in,
                              void* d_out, int out_size, void* d_ws, size_t ws_size,
                              hipStream_t stream) {
    (void)in_sizes; (void)n_in; (void)out_size; (void)ws_size;
    const float* x      = (const float*)d_in[0];
    const float* conv_w = (const float*)d_in[1];
    const float* gn_w   = (const float*)d_in[2];
    const float* gn_b   = (const float*)d_in[3];
    const float* emb    = (const float*)d_in[4];
    float* out = (float*)d_out;
    float* ws  = (float*)d_ws;

    hipLaunchKernelGGL(k_init,   dim3(7),         dim3(256), 0, stream, ws);
    hipLaunchKernelGGL(k_esq,    dim3(160),       dim3(256), 0, stream, emb, ws);
    hipLaunchKernelGGL(k_gemm,   dim3(256, 2, 2), dim3(256), 0, stream, x, conv_w, out, ws);
    hipLaunchKernelGGL(k_stats,  dim3(1),         dim3(64),  0, stream, ws);
    hipLaunchKernelGGL(k_vq,     dim3(256, 2),    dim3(256), 0, stream, emb, gn_w, gn_b, out, ws);
    hipLaunchKernelGGL(k_gather, dim3(512),       dim3(256), 0, stream, emb, out);
    hipLaunchKernelGGL(k_final,  dim3(1),         dim3(512), 0, stream, out, ws);
}